// Round 1
// baseline (97.990 us; speedup 1.0000x reference)
//
#include <hip/hip_runtime.h>
#include <stdint.h>

#define T_TOK 8192
#define DM    1024
#define NE    8
#define BOT   64
#define HD    512   // NE*BOT

typedef __attribute__((ext_vector_type(8))) short bf16x8;
typedef __attribute__((ext_vector_type(4))) float f32x4;

__device__ __forceinline__ ushort f2bf(float f) {
  union { float f; uint32_t u; } v; v.f = f;
  uint32_t r = (v.u + 0x7fffu + ((v.u >> 16) & 1u)) >> 16;
  return (ushort)r;
}

// ---- fp32 -> bf16 convert (X), 8 elems/thread -------------------------------
__global__ void cvt_x_kernel(const float* __restrict__ in, ushort* __restrict__ out, int n8) {
  int i = blockIdx.x * blockDim.x + threadIdx.x;
  if (i >= n8) return;
  const float4* p = (const float4*)in + (size_t)i * 2;
  float4 a = p[0], b = p[1];
  bf16x8 r;
  r[0]=f2bf(a.x); r[1]=f2bf(a.y); r[2]=f2bf(a.z); r[3]=f2bf(a.w);
  r[4]=f2bf(b.x); r[5]=f2bf(b.y); r[6]=f2bf(b.z); r[7]=f2bf(b.w);
  *(bf16x8*)(out + (size_t)i * 8) = r;
}

// ---- WdT[n][d] = Wd[e][d][b], n = e*64+b  (bf16, [512][1024]) ---------------
__global__ void cvt_wdT_kernel(const float* __restrict__ Wd, ushort* __restrict__ WdT) {
  int idx = blockIdx.x * blockDim.x + threadIdx.x;   // < 512*1024
  int n = idx >> 10, d = idx & 1023;
  int e = n >> 6, b = n & 63;
  WdT[idx] = f2bf(Wd[((size_t)e * DM + d) * BOT + b]);
}

// ---- WuT[d][n] = Wu[e][b][d] = Wu_flat[n*1024+d]  (bf16, [1024][512]) -------
__global__ void cvt_wuT_kernel(const float* __restrict__ Wu, ushort* __restrict__ WuT) {
  int idx = blockIdx.x * blockDim.x + threadIdx.x;   // < 1024*512
  int d = idx >> 9, n = idx & 511;
  WuT[idx] = f2bf(Wu[(size_t)n * DM + d]);
}

// ---- gating: logits = x_t @ w_gate, top-2, softmax, *0.5 -> sg[T][8] --------
__global__ void gating_kernel(const float* __restrict__ x, const float* __restrict__ wg,
                              float* __restrict__ sg) {
  const int lane = threadIdx.x & 63;
  const int wv   = threadIdx.x >> 6;
  const int t    = blockIdx.x * 4 + wv;
  const float* xr = x + (size_t)t * DM;
  float acc[NE];
  #pragma unroll
  for (int e = 0; e < NE; ++e) acc[e] = 0.f;
  #pragma unroll 4
  for (int i = 0; i < DM / 64; ++i) {
    int d = i * 64 + lane;
    float xv = xr[d];
    float4 w0 = *(const float4*)(wg + (size_t)d * NE);
    float4 w1 = *(const float4*)(wg + (size_t)d * NE + 4);
    acc[0] += xv * w0.x; acc[1] += xv * w0.y; acc[2] += xv * w0.z; acc[3] += xv * w0.w;
    acc[4] += xv * w1.x; acc[5] += xv * w1.y; acc[6] += xv * w1.z; acc[7] += xv * w1.w;
  }
  #pragma unroll
  for (int off = 32; off > 0; off >>= 1) {
    #pragma unroll
    for (int e = 0; e < NE; ++e) acc[e] += __shfl_xor(acc[e], off);
  }
  if (lane == 0) {
    // top-2 with jax tie-break (lower index wins on ties -> strict >)
    int e0 = 0; float l0 = acc[0];
    #pragma unroll
    for (int e = 1; e < NE; ++e) if (acc[e] > l0) { l0 = acc[e]; e0 = e; }
    int e1 = -1; float l1 = -3.4e38f;
    #pragma unroll
    for (int e = 0; e < NE; ++e) if (e != e0 && acc[e] > l1) { l1 = acc[e]; e1 = e; }
    float p1 = __expf(l1 - l0);           // l0 >= l1, stable
    float inv = 1.f / (1.f + p1);
    float g0 = 0.5f * inv;                 // ADAPTER_SCALE folded in
    float g1 = 0.5f * p1 * inv;
    #pragma unroll
    for (int e = 0; e < NE; ++e)
      sg[(size_t)t * NE + e] = (e == e0) ? g0 : ((e == e1) ? g1 : 0.f);
  }
}

// ---- 128x128-tile bf16 GEMM, C = A @ B^T, m97-style -------------------------
// A: [M][K] bf16 row-major; B: [N][K] bf16 row-major (i.e. B^T of the math B)
// EPI=0: Hout[t][n] = f2bf( sg[t][n>>6] * relu(acc + bd[n]) )
// EPI=1: Cout[t][d] = acc + sum_e sg[t][e]*bu[e][d]
template <int EPI>
__global__ __launch_bounds__(256)
void gemm_bt(const ushort* __restrict__ A, const ushort* __restrict__ B,
             int M, int N, int K,
             const float* __restrict__ sg, const float* __restrict__ bd,
             const float* __restrict__ bu,
             ushort* __restrict__ Hout, float* __restrict__ Cout) {
  __shared__ __attribute__((aligned(16))) ushort sA[128 * 64];
  __shared__ __attribute__((aligned(16))) ushort sB[128 * 64];
  const int lane = threadIdx.x & 63;
  const int w    = threadIdx.x >> 6;
  const int tile_m = blockIdx.y * 128;
  const int tile_n = blockIdx.x * 128;
  const int wm = (w >> 1) * 64;
  const int wn = (w & 1) * 64;
  const int sr = lane >> 3;          // staging: row within 8-row chunk
  const int sc = (lane & 7) * 8;     // staging: elem col
  const int lr = lane & 15;
  const int kg = lane >> 4;

  f32x4 acc[4][4] = {};

  const int nkt = K >> 6;
  for (int kt = 0; kt < nkt; ++kt) {
    const int k0 = kt << 6;
    #pragma unroll
    for (int c4 = 0; c4 < 4; ++c4) {
      int c = w * 4 + c4;
      const ushort* ga = A + (size_t)(tile_m + c * 8 + sr) * K + k0 + sc;
      __builtin_amdgcn_global_load_lds((__attribute__((address_space(1))) void*)ga,
                                       (__attribute__((address_space(3))) void*)&sA[c * 512],
                                       16, 0, 0);
      const ushort* gb = B + (size_t)(tile_n + c * 8 + sr) * K + k0 + sc;
      __builtin_amdgcn_global_load_lds((__attribute__((address_space(1))) void*)gb,
                                       (__attribute__((address_space(3))) void*)&sB[c * 512],
                                       16, 0, 0);
    }
    __syncthreads();
    #pragma unroll
    for (int s = 0; s < 2; ++s) {
      bf16x8 af[4], bfr[4];
      #pragma unroll
      for (int i = 0; i < 4; ++i)
        af[i] = *(const bf16x8*)&sA[(wm + i * 16 + lr) * 64 + s * 32 + kg * 8];
      #pragma unroll
      for (int j = 0; j < 4; ++j)
        bfr[j] = *(const bf16x8*)&sB[(wn + j * 16 + lr) * 64 + s * 32 + kg * 8];
      #pragma unroll
      for (int i = 0; i < 4; ++i)
        #pragma unroll
        for (int j = 0; j < 4; ++j)
          acc[i][j] = __builtin_amdgcn_mfma_f32_16x16x32_bf16(af[i], bfr[j], acc[i][j], 0, 0, 0);
    }
    __syncthreads();
  }

  // epilogue: C/D layout col=lane&15, row=(lane>>4)*4+reg  [measured m89/m91]
  if (EPI == 0) {
    #pragma unroll
    for (int j = 0; j < 4; ++j) {
      int col = tile_n + wn + j * 16 + lr;     // n in [0,512)
      int e = col >> 6;
      float bdv = bd[col];
      #pragma unroll
      for (int i = 0; i < 4; ++i) {
        #pragma unroll
        for (int r = 0; r < 4; ++r) {
          int t = tile_m + wm + i * 16 + kg * 4 + r;
          float v = fmaxf(acc[i][j][r] + bdv, 0.f) * sg[(size_t)t * NE + e];
          Hout[(size_t)t * HD + col] = f2bf(v);
        }
      }
    }
  } else {
    #pragma unroll
    for (int j = 0; j < 4; ++j) {
      int col = tile_n + wn + j * 16 + lr;     // d in [0,1024)
      #pragma unroll
      for (int i = 0; i < 4; ++i) {
        #pragma unroll
        for (int r = 0; r < 4; ++r) {
          int t = tile_m + wm + i * 16 + kg * 4 + r;
          float bias = 0.f;
          #pragma unroll
          for (int e = 0; e < NE; ++e)
            bias += sg[(size_t)t * NE + e] * bu[(size_t)e * DM + col];
          Cout[(size_t)t * DM + col] = acc[i][j][r] + bias;
        }
      }
    }
  }
}

extern "C" void kernel_launch(void* const* d_in, const int* in_sizes, int n_in,
                              void* d_out, int out_size, void* d_ws, size_t ws_size,
                              hipStream_t stream) {
  const float* x  = (const float*)d_in[0];
  const float* wg = (const float*)d_in[1];
  // d_in[2] = w_noise: unused (reference gates on clean logits)
  const float* Wd = (const float*)d_in[3];
  const float* bd = (const float*)d_in[4];
  const float* Wu = (const float*)d_in[5];
  const float* bu = (const float*)d_in[6];
  float* out = (float*)d_out;

  char* ws = (char*)d_ws;
  ushort* Xb  = (ushort*)ws;                                   // 16 MB
  ushort* H   = (ushort*)(ws + (size_t)16777216);              //  8 MB
  ushort* WdT = (ushort*)(ws + (size_t)16777216 + 8388608);    //  1 MB
  ushort* WuT = (ushort*)(ws + (size_t)16777216 + 8388608 + 1048576);
  float*  sg  = (float*) (ws + (size_t)16777216 + 8388608 + 2097152);  // 256 KB

  cvt_x_kernel  <<<dim3(4096), dim3(256), 0, stream>>>(x, Xb, T_TOK * DM / 8);
  cvt_wdT_kernel<<<dim3(2048), dim3(256), 0, stream>>>(Wd, WdT);
  cvt_wuT_kernel<<<dim3(2048), dim3(256), 0, stream>>>(Wu, WuT);
  gating_kernel <<<dim3(T_TOK / 4), dim3(256), 0, stream>>>(x, wg, sg);

  // H' = sg .* relu(X @ Wd_all + bd):  M=8192 N=512 K=1024
  gemm_bt<0><<<dim3(HD / 128, T_TOK / 128), dim3(256), 0, stream>>>(
      Xb, WdT, T_TOK, HD, DM, sg, bd, nullptr, H, nullptr);
  // out = H' @ Wu_all + sg @ bu:  M=8192 N=1024 K=512
  gemm_bt<1><<<dim3(DM / 128, T_TOK / 128), dim3(256), 0, stream>>>(
      H, WuT, T_TOK, DM, HD, sg, nullptr, bu, nullptr, out);
}

// Round 2
// 88.680 us; speedup vs baseline: 1.1050x; 1.1050x over previous
//
#include <hip/hip_runtime.h>
#include <stdint.h>

#define T_TOK 8192
#define DM    1024
#define NE    8
#define BOT   64
#define HD    512
#define HD2   576   // 512 expert cols + 8 sg cols + 56 zero pad (bias folded into K)

typedef __attribute__((ext_vector_type(8))) short bf16x8;
typedef __attribute__((ext_vector_type(4))) float f32x4;

__device__ __forceinline__ ushort f2bf(float f) {
  union { float f; uint32_t u; } v; v.f = f;
  uint32_t r = (v.u + 0x7fffu + ((v.u >> 16) & 1u)) >> 16;
  return (ushort)r;
}

// ---- fused: X fp32->bf16, gating logits, top-2 softmax, H2 tail cols --------
// 4 tokens/block (1 per wave); lane owns 16 consecutive elems of the row.
__global__ __launch_bounds__(256)
void prep_kernel(const float* __restrict__ x, const float* __restrict__ wg,
                 ushort* __restrict__ Xb, float* __restrict__ sg,
                 ushort* __restrict__ H2) {
  const int lane = threadIdx.x & 63;
  const int wv   = threadIdx.x >> 6;
  const int t    = blockIdx.x * 4 + wv;
  const float* xr = x + (size_t)t * DM;
  const int d0 = lane * 16;
  float4 xa[4];
  #pragma unroll
  for (int i = 0; i < 4; ++i) xa[i] = *(const float4*)(xr + d0 + i * 4);
  bf16x8 rA, rB;
  #pragma unroll
  for (int k = 0; k < 8; ++k) rA[k] = (short)f2bf(((const float*)xa)[k]);
  #pragma unroll
  for (int k = 0; k < 8; ++k) rB[k] = (short)f2bf(((const float*)xa)[k + 8]);
  *(bf16x8*)(Xb + (size_t)t * DM + d0)     = rA;
  *(bf16x8*)(Xb + (size_t)t * DM + d0 + 8) = rB;
  float acc[NE] = {};
  #pragma unroll
  for (int k = 0; k < 16; ++k) {
    const float xv = ((const float*)xa)[k];
    const float* wr = wg + (size_t)(d0 + k) * NE;
    float4 w0 = *(const float4*)wr, w1 = *(const float4*)(wr + 4);
    acc[0] += xv * w0.x; acc[1] += xv * w0.y; acc[2] += xv * w0.z; acc[3] += xv * w0.w;
    acc[4] += xv * w1.x; acc[5] += xv * w1.y; acc[6] += xv * w1.z; acc[7] += xv * w1.w;
  }
  #pragma unroll
  for (int off = 32; off; off >>= 1)
    #pragma unroll
    for (int e = 0; e < NE; ++e) acc[e] += __shfl_xor(acc[e], off);
  // all lanes hold identical sums -> uniform top-2 (strict > = lower idx wins ties)
  int e0 = 0; float l0 = acc[0];
  #pragma unroll
  for (int e = 1; e < NE; ++e) if (acc[e] > l0) { l0 = acc[e]; e0 = e; }
  int e1 = -1; float l1 = -3.4e38f;
  #pragma unroll
  for (int e = 0; e < NE; ++e) if (e != e0 && acc[e] > l1) { l1 = acc[e]; e1 = e; }
  const float p1  = __expf(l1 - l0);
  const float inv = 1.f / (1.f + p1);
  const float g0 = 0.5f * inv, g1 = 0.5f * p1 * inv;   // ADAPTER_SCALE folded
  float g = 0.f;
  if (lane == e0) g = g0;
  if (lane == e1) g = g1;
  if (lane < NE) sg[(size_t)t * NE + lane] = g;
  H2[(size_t)t * HD2 + HD + lane] = (lane < NE) ? f2bf(g) : (ushort)0;
}

// ---- WdT[e*64+b][d] = bf16(Wd[e][d][b]) — LDS-tiled transpose ---------------
__global__ __launch_bounds__(256)
void cvt_wd_kernel(const float* __restrict__ Wd, ushort* __restrict__ WdT) {
  __shared__ ushort tl[64][72];
  const int e  = blockIdx.y;
  const int d0 = blockIdx.x * 64;
  const int rr = threadIdx.x >> 2;
  const int cc = (threadIdx.x & 3) * 16;
  const float* src = Wd + ((size_t)e * DM + d0 + rr) * BOT + cc;
  #pragma unroll
  for (int i = 0; i < 4; ++i) {
    float4 v = *(const float4*)(src + i * 4);
    tl[rr][cc + i * 4 + 0] = f2bf(v.x);
    tl[rr][cc + i * 4 + 1] = f2bf(v.y);
    tl[rr][cc + i * 4 + 2] = f2bf(v.z);
    tl[rr][cc + i * 4 + 3] = f2bf(v.w);
  }
  __syncthreads();
  bf16x8 o0, o1;
  #pragma unroll
  for (int k = 0; k < 8; ++k) o0[k] = (short)tl[cc + k][rr];
  #pragma unroll
  for (int k = 0; k < 8; ++k) o1[k] = (short)tl[cc + 8 + k][rr];
  ushort* dst = WdT + ((size_t)e * BOT + rr) * DM + d0 + cc;
  *(bf16x8*)dst       = o0;
  *(bf16x8*)(dst + 8) = o1;
}

// ---- Wu2T[d][n] (ld=576): n<512 -> Wu[n][d]; 512..519 -> bu; else 0 ---------
__global__ __launch_bounds__(256)
void cvt_wu_kernel(const float* __restrict__ Wu, const float* __restrict__ bu,
                   ushort* __restrict__ W2) {
  __shared__ ushort tl[64][72];
  const int n0 = blockIdx.y * 64;
  const int d0 = blockIdx.x * 64;
  const int rr = threadIdx.x >> 2;
  const int cc = (threadIdx.x & 3) * 16;
  const int n  = n0 + rr;
  #pragma unroll
  for (int i = 0; i < 4; ++i) {
    float4 v;
    if (n < HD)           v = *(const float4*)(Wu + (size_t)n * DM + d0 + cc + i * 4);
    else if (n < HD + NE) v = *(const float4*)(bu + (size_t)(n - HD) * DM + d0 + cc + i * 4);
    else { v.x = 0.f; v.y = 0.f; v.z = 0.f; v.w = 0.f; }
    tl[rr][cc + i * 4 + 0] = f2bf(v.x);
    tl[rr][cc + i * 4 + 1] = f2bf(v.y);
    tl[rr][cc + i * 4 + 2] = f2bf(v.z);
    tl[rr][cc + i * 4 + 3] = f2bf(v.w);
  }
  __syncthreads();
  bf16x8 o0, o1;
  #pragma unroll
  for (int k = 0; k < 8; ++k) o0[k] = (short)tl[cc + k][rr];
  #pragma unroll
  for (int k = 0; k < 8; ++k) o1[k] = (short)tl[cc + 8 + k][rr];
  ushort* dst = W2 + (size_t)(d0 + rr) * HD2 + n0 + cc;
  *(bf16x8*)dst       = o0;
  *(bf16x8*)(dst + 8) = o1;
}

// ---- 128x128 bf16 GEMM, C = A @ B^T, double-buffered + counted vmcnt --------
// A:[M][K], B:[N][K] bf16, K = NKT*64, lda=ldb=K.
// EPI=0: Hout[t][col] (ld 576) = bf16( relu(acc+bd[col]) * sg[t][col>>6] )
// EPI=1: Cout[t][col] (ld 1024) = acc   (bias already folded into K)
template <int EPI, int NKT>
__global__ __launch_bounds__(256)
void gemm_bt(const ushort* __restrict__ A, const ushort* __restrict__ B,
             const float* __restrict__ sg, const float* __restrict__ bd,
             ushort* __restrict__ Hout, float* __restrict__ Cout) {
  constexpr int K = NKT * 64;
  __shared__ __attribute__((aligned(16))) ushort sA[2][128 * 64];
  __shared__ __attribute__((aligned(16))) ushort sB[2][128 * 64];
  const int lane = threadIdx.x & 63;
  const int w    = threadIdx.x >> 6;
  const int tile_m = blockIdx.y * 128;
  const int tile_n = blockIdx.x * 128;
  const int wm = (w >> 1) * 64;
  const int wn = (w & 1) * 64;
  const int sr = lane >> 3;
  const int sc = (lane & 7) * 8;
  const int lr = lane & 15;
  const int kg = lane >> 4;
  f32x4 acc[4][4] = {};

#define STAGE(buf, kt) do {                                                       \
    const int k0_ = (kt) << 6;                                                    \
    _Pragma("unroll")                                                             \
    for (int c = 0; c < 4; ++c) {                                                 \
      const ushort* ga = A + (size_t)(tile_m + w * 32 + c * 8 + sr) * K + k0_ + sc; \
      __builtin_amdgcn_global_load_lds((const __attribute__((address_space(1))) void*)ga, \
          (__attribute__((address_space(3))) void*)&sA[buf][(w * 32 + c * 8) * 64], 16, 0, 0); \
      const ushort* gb = B + (size_t)(tile_n + w * 32 + c * 8 + sr) * K + k0_ + sc; \
      __builtin_amdgcn_global_load_lds((const __attribute__((address_space(1))) void*)gb, \
          (__attribute__((address_space(3))) void*)&sB[buf][(w * 32 + c * 8) * 64], 16, 0, 0); \
    } } while (0)

  STAGE(0, 0);
  for (int kt = 0; kt < NKT; ++kt) {
    const int cur = kt & 1;
    if (kt + 1 < NKT) {
      STAGE(cur ^ 1, kt + 1);                       // next tile in flight
      asm volatile("s_waitcnt vmcnt(8)" ::: "memory");  // current tile's 8 landed
    } else {
      asm volatile("s_waitcnt vmcnt(0)" ::: "memory");
    }
    __builtin_amdgcn_s_barrier();
    #pragma unroll
    for (int s = 0; s < 2; ++s) {
      bf16x8 af[4], bfr[4];
      #pragma unroll
      for (int i = 0; i < 4; ++i)
        af[i] = *(const bf16x8*)&sA[cur][(wm + i * 16 + lr) * 64 + s * 32 + kg * 8];
      #pragma unroll
      for (int j = 0; j < 4; ++j)
        bfr[j] = *(const bf16x8*)&sB[cur][(wn + j * 16 + lr) * 64 + s * 32 + kg * 8];
      #pragma unroll
      for (int i = 0; i < 4; ++i)
        #pragma unroll
        for (int j = 0; j < 4; ++j)
          acc[i][j] = __builtin_amdgcn_mfma_f32_16x16x32_bf16(af[i], bfr[j], acc[i][j], 0, 0, 0);
    }
    asm volatile("" ::: "memory");       // reads of buf[cur] can't sink past barrier
    __builtin_amdgcn_s_barrier();        // protects buf[cur] from next STAGE
  }
#undef STAGE

  if (EPI == 0) {
    const int e = (tile_n + wn) >> 6;    // one expert per wave column-block
    float bdv[4];
    #pragma unroll
    for (int j = 0; j < 4; ++j) bdv[j] = bd[tile_n + wn + j * 16 + lr];
    #pragma unroll
    for (int i = 0; i < 4; ++i) {
      #pragma unroll
      for (int r = 0; r < 4; ++r) {
        const int t = tile_m + wm + i * 16 + kg * 4 + r;
        const float sgl = sg[(size_t)t * NE + e];
        #pragma unroll
        for (int j = 0; j < 4; ++j) {
          float v = fmaxf(acc[i][j][r] + bdv[j], 0.f) * sgl;
          Hout[(size_t)t * HD2 + tile_n + wn + j * 16 + lr] = f2bf(v);
        }
      }
    }
  } else {
    #pragma unroll
    for (int i = 0; i < 4; ++i) {
      #pragma unroll
      for (int r = 0; r < 4; ++r) {
        const int t = tile_m + wm + i * 16 + kg * 4 + r;
        #pragma unroll
        for (int j = 0; j < 4; ++j)
          Cout[(size_t)t * DM + tile_n + wn + j * 16 + lr] = acc[i][j][r];
      }
    }
  }
}

extern "C" void kernel_launch(void* const* d_in, const int* in_sizes, int n_in,
                              void* d_out, int out_size, void* d_ws, size_t ws_size,
                              hipStream_t stream) {
  const float* x  = (const float*)d_in[0];
  const float* wg = (const float*)d_in[1];
  // d_in[2] = w_noise: unused (reference gates on clean logits)
  const float* Wd = (const float*)d_in[3];
  const float* bd = (const float*)d_in[4];
  const float* Wu = (const float*)d_in[5];
  const float* bu = (const float*)d_in[6];
  float* out = (float*)d_out;

  char* ws = (char*)d_ws;
  ushort* Xb   = (ushort*)(ws);                      // 16 MB
  ushort* H2   = (ushort*)(ws + 16777216);           // 8192*576*2 = 9.44 MB
  ushort* WdT  = (ushort*)(ws + 26214400);           // 1 MB
  ushort* Wu2T = (ushort*)(ws + 27262976);           // 1.18 MB
  float*  sgw  = (float*) (ws + 28442624);           // 256 KB

  prep_kernel  <<<dim3(T_TOK / 4), dim3(256), 0, stream>>>(x, wg, Xb, sgw, H2);
  cvt_wd_kernel<<<dim3(16, 8),     dim3(256), 0, stream>>>(Wd, WdT);
  cvt_wu_kernel<<<dim3(16, 9),     dim3(256), 0, stream>>>(Wu, bu, Wu2T);

  // H2[:, :512] = sg .* relu(X @ WdT^T + bd):  M=8192 N=512 K=1024
  gemm_bt<0, 16><<<dim3(4, 64), dim3(256), 0, stream>>>(Xb, WdT, sgw, bd, H2, nullptr);
  // out = H2 @ Wu2T^T (bias rows folded):      M=8192 N=1024 K=576
  gemm_bt<1, 9><<<dim3(8, 64), dim3(256), 0, stream>>>(H2, Wu2T, sgw, nullptr, nullptr, out);
}

// Round 3
// 77.406 us; speedup vs baseline: 1.2659x; 1.1457x over previous
//
#include <hip/hip_runtime.h>
#include <stdint.h>

#define T_TOK 8192
#define DM    1024
#define NE    8
#define BOT   64
#define HD    512
#define HD2   576   // 512 expert cols + 8 sg cols + 56 zero pad (bias folded into K)
#define PW    16    // tokens per prep block

typedef __attribute__((ext_vector_type(8))) short bf16x8;
typedef __attribute__((ext_vector_type(4))) short bf16x4;
typedef __attribute__((ext_vector_type(4))) float f32x4;

__device__ __forceinline__ ushort f2bf(float f) {
  union { float f; uint32_t u; } v; v.f = f;
  uint32_t r = (v.u + 0x7fffu + ((v.u >> 16) & 1u)) >> 16;
  return (ushort)r;
}

// ---- fused prep: X->bf16, fp32 gating (reg-resident wg), top-2, H2 tail ----
// 4 waves/block; wave w owns d-slice [w*256, w*256+256); lane owns 4 consecutive d.
// wg rows for the lane's 4 d's live in registers for the whole kernel.
__global__ __launch_bounds__(256)
void prep_kernel(const float* __restrict__ x, const float* __restrict__ wg,
                 ushort* __restrict__ Xb, float* __restrict__ sg,
                 ushort* __restrict__ H2) {
  __shared__ float part[4][PW][NE];
  __shared__ float sgl[PW][NE];
  const int lane = threadIdx.x & 63;
  const int w    = threadIdx.x >> 6;
  const int t0   = blockIdx.x * PW;
  const int dd   = w * 256 + lane * 4;

  // wg rows for my 4 d's -> 32 VGPRs (one-time, L2-hot)
  float4 wgr[4][2];
  #pragma unroll
  for (int j = 0; j < 4; ++j) {
    wgr[j][0] = *(const float4*)(wg + (size_t)(dd + j) * NE);
    wgr[j][1] = *(const float4*)(wg + (size_t)(dd + j) * NE + 4);
  }
  const int ebit = ((lane & 1) << 2) | (lane & 2) | ((lane >> 2) & 1);

  const float* xp = x + (size_t)t0 * DM + dd;
  float4 xv = *(const float4*)xp;
  for (int tk = 0; tk < PW; ++tk) {
    float4 nxt;
    if (tk + 1 < PW) nxt = *(const float4*)(xp + (size_t)(tk + 1) * DM);
    // convert + store bf16 (coalesced b64)
    bf16x4 xb;
    xb[0] = (short)f2bf(xv.x); xb[1] = (short)f2bf(xv.y);
    xb[2] = (short)f2bf(xv.z); xb[3] = (short)f2bf(xv.w);
    *(bf16x4*)(Xb + (size_t)(t0 + tk) * DM + dd) = xb;
    // fp32 partial logits
    float a[NE] = {};
    const float* xs = (const float*)&xv;
    #pragma unroll
    for (int j = 0; j < 4; ++j) {
      const float xj = xs[j];
      const float* wr = (const float*)&wgr[j][0];
      #pragma unroll
      for (int e = 0; e < NE; ++e) a[e] += xj * wr[e];
    }
    // halving butterfly: 8 vals over 64 lanes -> lane holds expert bitrev3(lane&7)
    float t0v[4];
    #pragma unroll
    for (int j = 0; j < 4; ++j) {
      float send = (lane & 1) ? a[j] : a[j + 4];
      float keep = (lane & 1) ? a[j + 4] : a[j];
      t0v[j] = keep + __shfl_xor(send, 1);
    }
    float t1v[2];
    #pragma unroll
    for (int j = 0; j < 2; ++j) {
      float send = (lane & 2) ? t1v[0] * 0.f + t0v[j] : t0v[j + 2];
      float keep = (lane & 2) ? t0v[j + 2] : t0v[j];
      t1v[j] = keep + __shfl_xor(send, 2);
    }
    {
      float send = (lane & 4) ? t1v[0] : t1v[1];
      float keep = (lane & 4) ? t1v[1] : t1v[0];
      float t2 = keep + __shfl_xor(send, 4);
      t2 += __shfl_xor(t2, 8);
      t2 += __shfl_xor(t2, 16);
      t2 += __shfl_xor(t2, 32);
      if (lane < NE) part[w][tk][ebit] = t2;
    }
    xv = nxt;
  }
  __syncthreads();

  // finalize: 1 thread per token (fp32-exact top-2, jax tie-break = strict >)
  const int tid = threadIdx.x;
  if (tid < PW) {
    float lg[NE];
    #pragma unroll
    for (int e = 0; e < NE; ++e)
      lg[e] = part[0][tid][e] + part[1][tid][e] + part[2][tid][e] + part[3][tid][e];
    int e0 = 0; float l0 = lg[0];
    #pragma unroll
    for (int e = 1; e < NE; ++e) if (lg[e] > l0) { l0 = lg[e]; e0 = e; }
    int e1 = -1; float l1 = -3.4e38f;
    #pragma unroll
    for (int e = 0; e < NE; ++e) if (e != e0 && lg[e] > l1) { l1 = lg[e]; e1 = e; }
    const float p1  = __expf(l1 - l0);
    const float inv = 1.f / (1.f + p1);
    const float g0 = 0.5f * inv, g1 = 0.5f * p1 * inv;  // ADAPTER_SCALE folded
    float g[NE];
    #pragma unroll
    for (int e = 0; e < NE; ++e) g[e] = (e == e0) ? g0 : ((e == e1) ? g1 : 0.f);
    #pragma unroll
    for (int e = 0; e < NE; ++e) sgl[tid][e] = g[e];
    *(float4*)(sg + (size_t)(t0 + tid) * NE)     = *(float4*)&g[0];
    *(float4*)(sg + (size_t)(t0 + tid) * NE + 4) = *(float4*)&g[4];
  }
  __syncthreads();

  // H2 tail cols [512,576): 8 bf16 gates then zeros; vectorized b128 writes
  if (tid < PW * 8) {
    const int tk = tid >> 3, ch = tid & 7;
    bf16x8 v;
    #pragma unroll
    for (int k = 0; k < 8; ++k)
      v[k] = (ch == 0) ? (short)f2bf(sgl[tk][k]) : (short)0;
    *(bf16x8*)(H2 + (size_t)(t0 + tk) * HD2 + HD + ch * 8) = v;
  }
}

// ---- WdT[e*64+b][d] = bf16(Wd[e][d][b]) — LDS-tiled transpose ---------------
__global__ __launch_bounds__(256)
void cvt_wd_kernel(const float* __restrict__ Wd, ushort* __restrict__ WdT) {
  __shared__ ushort tl[64][72];
  const int e  = blockIdx.y;
  const int d0 = blockIdx.x * 64;
  const int rr = threadIdx.x >> 2;
  const int cc = (threadIdx.x & 3) * 16;
  const float* src = Wd + ((size_t)e * DM + d0 + rr) * BOT + cc;
  #pragma unroll
  for (int i = 0; i < 4; ++i) {
    float4 v = *(const float4*)(src + i * 4);
    tl[rr][cc + i * 4 + 0] = f2bf(v.x);
    tl[rr][cc + i * 4 + 1] = f2bf(v.y);
    tl[rr][cc + i * 4 + 2] = f2bf(v.z);
    tl[rr][cc + i * 4 + 3] = f2bf(v.w);
  }
  __syncthreads();
  bf16x8 o0, o1;
  #pragma unroll
  for (int k = 0; k < 8; ++k) o0[k] = (short)tl[cc + k][rr];
  #pragma unroll
  for (int k = 0; k < 8; ++k) o1[k] = (short)tl[cc + 8 + k][rr];
  ushort* dst = WdT + ((size_t)e * BOT + rr) * DM + d0 + cc;
  *(bf16x8*)dst       = o0;
  *(bf16x8*)(dst + 8) = o1;
}

// ---- Wu2T[d][n] (ld=576): n<512 -> Wu[n][d]; 512..519 -> bu; else 0 ---------
__global__ __launch_bounds__(256)
void cvt_wu_kernel(const float* __restrict__ Wu, const float* __restrict__ bu,
                   ushort* __restrict__ W2) {
  __shared__ ushort tl[64][72];
  const int n0 = blockIdx.y * 64;
  const int d0 = blockIdx.x * 64;
  const int rr = threadIdx.x >> 2;
  const int cc = (threadIdx.x & 3) * 16;
  const int n  = n0 + rr;
  #pragma unroll
  for (int i = 0; i < 4; ++i) {
    float4 v;
    if (n < HD)           v = *(const float4*)(Wu + (size_t)n * DM + d0 + cc + i * 4);
    else if (n < HD + NE) v = *(const float4*)(bu + (size_t)(n - HD) * DM + d0 + cc + i * 4);
    else { v.x = 0.f; v.y = 0.f; v.z = 0.f; v.w = 0.f; }
    tl[rr][cc + i * 4 + 0] = f2bf(v.x);
    tl[rr][cc + i * 4 + 1] = f2bf(v.y);
    tl[rr][cc + i * 4 + 2] = f2bf(v.z);
    tl[rr][cc + i * 4 + 3] = f2bf(v.w);
  }
  __syncthreads();
  bf16x8 o0, o1;
  #pragma unroll
  for (int k = 0; k < 8; ++k) o0[k] = (short)tl[cc + k][rr];
  #pragma unroll
  for (int k = 0; k < 8; ++k) o1[k] = (short)tl[cc + 8 + k][rr];
  ushort* dst = W2 + (size_t)(d0 + rr) * HD2 + n0 + cc;
  *(bf16x8*)dst       = o0;
  *(bf16x8*)(dst + 8) = o1;
}

// ---- 128x128 bf16 GEMM, C = A @ B^T, dbuf + counted vmcnt + XCD swizzle -----
// NBX = N/128 tiles; grid is 1-D (NBX * M/128 blocks).
// EPI=0: Hout[t][col] (ld 576) = bf16( relu(acc+bd[col]) * sg[t][col>>6] )
// EPI=1: Cout[t][col] (ld 1024) = acc
template <int EPI, int NKT, int NBX>
__global__ __launch_bounds__(256)
void gemm_bt(const ushort* __restrict__ A, const ushort* __restrict__ B,
             const float* __restrict__ sg, const float* __restrict__ bd,
             ushort* __restrict__ Hout, float* __restrict__ Cout, int nwg) {
  constexpr int K = NKT * 64;
  __shared__ __attribute__((aligned(16))) ushort sA[2][128 * 64];
  __shared__ __attribute__((aligned(16))) ushort sB[2][128 * 64];
  const int lane = threadIdx.x & 63;
  const int w    = threadIdx.x >> 6;
  // XCD-chunked swizzle (nwg % 8 == 0): contiguous logical chunk per XCD
  const int lb = (blockIdx.x % 8) * (nwg / 8) + blockIdx.x / 8;
  const int tile_m = (lb / NBX) * 128;
  const int tile_n = (lb % NBX) * 128;
  const int wm = (w >> 1) * 64;
  const int wn = (w & 1) * 64;
  const int sr = lane >> 3;
  const int sc = (lane & 7) * 8;
  const int lr = lane & 15;
  const int kg = lane >> 4;
  f32x4 acc[4][4] = {};

#define STAGE(buf, kt) do {                                                       \
    const int k0_ = (kt) << 6;                                                    \
    _Pragma("unroll")                                                             \
    for (int c = 0; c < 4; ++c) {                                                 \
      const ushort* ga = A + (size_t)(tile_m + w * 32 + c * 8 + sr) * K + k0_ + sc; \
      __builtin_amdgcn_global_load_lds((const __attribute__((address_space(1))) void*)ga, \
          (__attribute__((address_space(3))) void*)&sA[buf][(w * 32 + c * 8) * 64], 16, 0, 0); \
      const ushort* gb = B + (size_t)(tile_n + w * 32 + c * 8 + sr) * K + k0_ + sc; \
      __builtin_amdgcn_global_load_lds((const __attribute__((address_space(1))) void*)gb, \
          (__attribute__((address_space(3))) void*)&sB[buf][(w * 32 + c * 8) * 64], 16, 0, 0); \
    } } while (0)

  STAGE(0, 0);
  for (int kt = 0; kt < NKT; ++kt) {
    const int cur = kt & 1;
    if (kt + 1 < NKT) {
      STAGE(cur ^ 1, kt + 1);
      asm volatile("s_waitcnt vmcnt(8)" ::: "memory");
    } else {
      asm volatile("s_waitcnt vmcnt(0)" ::: "memory");
    }
    __builtin_amdgcn_s_barrier();
    #pragma unroll
    for (int s = 0; s < 2; ++s) {
      bf16x8 af[4], bfr[4];
      #pragma unroll
      for (int i = 0; i < 4; ++i)
        af[i] = *(const bf16x8*)&sA[cur][(wm + i * 16 + lr) * 64 + s * 32 + kg * 8];
      #pragma unroll
      for (int j = 0; j < 4; ++j)
        bfr[j] = *(const bf16x8*)&sB[cur][(wn + j * 16 + lr) * 64 + s * 32 + kg * 8];
      #pragma unroll
      for (int i = 0; i < 4; ++i)
        #pragma unroll
        for (int j = 0; j < 4; ++j)
          acc[i][j] = __builtin_amdgcn_mfma_f32_16x16x32_bf16(af[i], bfr[j], acc[i][j], 0, 0, 0);
    }
    asm volatile("" ::: "memory");
    __builtin_amdgcn_s_barrier();
  }
#undef STAGE

  if (EPI == 0) {
    const int e = (tile_n + wn) >> 6;
    float bdv[4];
    #pragma unroll
    for (int j = 0; j < 4; ++j) bdv[j] = bd[tile_n + wn + j * 16 + lr];
    #pragma unroll
    for (int i = 0; i < 4; ++i) {
      #pragma unroll
      for (int r = 0; r < 4; ++r) {
        const int t = tile_m + wm + i * 16 + kg * 4 + r;
        const float sglv = sg[(size_t)t * NE + e];
        #pragma unroll
        for (int j = 0; j < 4; ++j) {
          float v = fmaxf(acc[i][j][r] + bdv[j], 0.f) * sglv;
          Hout[(size_t)t * HD2 + tile_n + wn + j * 16 + lr] = f2bf(v);
        }
      }
    }
  } else {
    #pragma unroll
    for (int i = 0; i < 4; ++i) {
      #pragma unroll
      for (int r = 0; r < 4; ++r) {
        const int t = tile_m + wm + i * 16 + kg * 4 + r;
        #pragma unroll
        for (int j = 0; j < 4; ++j)
          Cout[(size_t)t * DM + tile_n + wn + j * 16 + lr] = acc[i][j][r];
      }
    }
  }
}

extern "C" void kernel_launch(void* const* d_in, const int* in_sizes, int n_in,
                              void* d_out, int out_size, void* d_ws, size_t ws_size,
                              hipStream_t stream) {
  const float* x  = (const float*)d_in[0];
  const float* wg = (const float*)d_in[1];
  // d_in[2] = w_noise: unused (reference gates on clean logits)
  const float* Wd = (const float*)d_in[3];
  const float* bd = (const float*)d_in[4];
  const float* Wu = (const float*)d_in[5];
  const float* bu = (const float*)d_in[6];
  float* out = (float*)d_out;

  char* ws = (char*)d_ws;
  ushort* Xb   = (ushort*)(ws);                      // 16 MB
  ushort* H2   = (ushort*)(ws + 16777216);           // 9.44 MB
  ushort* WdT  = (ushort*)(ws + 26214400);           // 1 MB
  ushort* Wu2T = (ushort*)(ws + 27262976);           // 1.18 MB
  float*  sgw  = (float*) (ws + 28442624);           // 256 KB

  prep_kernel  <<<dim3(T_TOK / PW), dim3(256), 0, stream>>>(x, wg, Xb, sgw, H2);
  cvt_wd_kernel<<<dim3(16, 8),      dim3(256), 0, stream>>>(Wd, WdT);
  cvt_wu_kernel<<<dim3(16, 9),      dim3(256), 0, stream>>>(Wu, bu, Wu2T);

  // H2[:, :512] = sg .* relu(X @ WdT^T + bd):  M=8192 N=512 K=1024
  gemm_bt<0, 16, 4><<<dim3(256), dim3(256), 0, stream>>>(Xb, WdT, sgw, bd, H2, nullptr, 256);
  // out = H2 @ Wu2T^T (bias rows folded):      M=8192 N=1024 K=576
  gemm_bt<1, 9, 8><<<dim3(512), dim3(256), 0, stream>>>(H2, Wu2T, sgw, nullptr, nullptr, out, 512);
}

// Round 4
// 55.543 us; speedup vs baseline: 1.7642x; 1.3936x over previous
//
#include <hip/hip_runtime.h>
#include <stdint.h>

#define T_TOK 8192
#define DM    1024
#define NE    8
#define BOT   64
#define HD    512
#define HD2   576   // 512 expert cols + 8 sg cols + 56 zero pad (bias folded into K)
#define PW    8     // tokens per prep block

typedef __attribute__((ext_vector_type(8))) short bf16x8;
typedef __attribute__((ext_vector_type(4))) short bf16x4;
typedef __attribute__((ext_vector_type(4))) float f32x4;

__device__ __forceinline__ ushort f2bf(float f) {
  union { float f; uint32_t u; } v; v.f = f;
  uint32_t r = (v.u + 0x7fffu + ((v.u >> 16) & 1u)) >> 16;
  return (ushort)r;
}

// ---- fused prep: X->bf16, fp32 gating (reg-resident wg), top-2, H2 tail ----
// 4 waves/block; wave w owns d-slice [w*256, w*256+256); lane owns 4 consecutive d.
// launch_bounds(256,2): VGPR cap 256 so wgr[4][2] (32 VGPRs) stays register-resident.
__global__ __launch_bounds__(256, 2)
void prep_kernel(const float* __restrict__ x, const float* __restrict__ wg,
                 ushort* __restrict__ Xb, float* __restrict__ sg,
                 ushort* __restrict__ H2) {
  __shared__ float part[4][PW][NE];
  __shared__ float sgl[PW][NE];
  const int lane = threadIdx.x & 63;
  const int w    = threadIdx.x >> 6;
  const int t0   = blockIdx.x * PW;
  const int dd   = w * 256 + lane * 4;

  float4 wgr[4][2];
  #pragma unroll
  for (int j = 0; j < 4; ++j) {
    wgr[j][0] = *(const float4*)(wg + (size_t)(dd + j) * NE);
    wgr[j][1] = *(const float4*)(wg + (size_t)(dd + j) * NE + 4);
  }
  const int ebit = ((lane & 1) << 2) | (lane & 2) | ((lane >> 2) & 1);

  const float* xp = x + (size_t)t0 * DM + dd;
  float4 xv = *(const float4*)xp;
  #pragma unroll
  for (int tk = 0; tk < PW; ++tk) {
    float4 nxt = {};
    if (tk + 1 < PW) nxt = *(const float4*)(xp + (size_t)(tk + 1) * DM);
    bf16x4 xb;
    xb[0] = (short)f2bf(xv.x); xb[1] = (short)f2bf(xv.y);
    xb[2] = (short)f2bf(xv.z); xb[3] = (short)f2bf(xv.w);
    *(bf16x4*)(Xb + (size_t)(t0 + tk) * DM + dd) = xb;
    float a[NE] = {};
    const float* xs = (const float*)&xv;
    #pragma unroll
    for (int j = 0; j < 4; ++j) {
      const float xj = xs[j];
      const float* wr = (const float*)&wgr[j][0];
      #pragma unroll
      for (int e = 0; e < NE; ++e) a[e] += xj * wr[e];
    }
    // halving butterfly: lane ends up holding expert ebit(lane&7)'s full sum
    float t0v[4];
    #pragma unroll
    for (int j = 0; j < 4; ++j) {
      float send = (lane & 1) ? a[j] : a[j + 4];
      float keep = (lane & 1) ? a[j + 4] : a[j];
      t0v[j] = keep + __shfl_xor(send, 1);
    }
    float t1v[2];
    #pragma unroll
    for (int j = 0; j < 2; ++j) {
      float send = (lane & 2) ? t0v[j] : t0v[j + 2];
      float keep = (lane & 2) ? t0v[j + 2] : t0v[j];
      t1v[j] = keep + __shfl_xor(send, 2);
    }
    {
      float send = (lane & 4) ? t1v[0] : t1v[1];
      float keep = (lane & 4) ? t1v[1] : t1v[0];
      float t2 = keep + __shfl_xor(send, 4);
      t2 += __shfl_xor(t2, 8);
      t2 += __shfl_xor(t2, 16);
      t2 += __shfl_xor(t2, 32);
      if (lane < NE) part[w][tk][ebit] = t2;
    }
    xv = nxt;
  }
  __syncthreads();

  const int tid = threadIdx.x;
  if (tid < PW) {
    float lg[NE];
    #pragma unroll
    for (int e = 0; e < NE; ++e)
      lg[e] = part[0][tid][e] + part[1][tid][e] + part[2][tid][e] + part[3][tid][e];
    int e0 = 0; float l0 = lg[0];
    #pragma unroll
    for (int e = 1; e < NE; ++e) if (lg[e] > l0) { l0 = lg[e]; e0 = e; }
    int e1 = -1; float l1 = -3.4e38f;
    #pragma unroll
    for (int e = 0; e < NE; ++e) if (e != e0 && lg[e] > l1) { l1 = lg[e]; e1 = e; }
    const float p1  = __expf(l1 - l0);
    const float inv = 1.f / (1.f + p1);
    const float g0 = 0.5f * inv, g1 = 0.5f * p1 * inv;   // ADAPTER_SCALE folded
    float g[NE];
    #pragma unroll
    for (int e = 0; e < NE; ++e) g[e] = (e == e0) ? g0 : ((e == e1) ? g1 : 0.f);
    #pragma unroll
    for (int e = 0; e < NE; ++e) sgl[tid][e] = g[e];
    *(float4*)(sg + (size_t)(t0 + tid) * NE)     = *(float4*)&g[0];
    *(float4*)(sg + (size_t)(t0 + tid) * NE + 4) = *(float4*)&g[4];
  }
  __syncthreads();

  if (tid < PW * 8) {
    const int tk = tid >> 3, ch = tid & 7;
    bf16x8 v;
    #pragma unroll
    for (int k = 0; k < 8; ++k)
      v[k] = (ch == 0) ? (short)f2bf(sgl[tk][k]) : (short)0;
    *(bf16x8*)(H2 + (size_t)(t0 + tk) * HD2 + HD + ch * 8) = v;
  }
}

// ---- merged weight transposes (one launch) ---------------------------------
// bx < 128:  WdT[e*64+b][d] = bf16(Wd[e][d][b])
// bx >= 128: Wu2T[d][n] (ld 576): n<512 -> Wu[n][d]; 512..519 -> bu; else 0
__global__ __launch_bounds__(256)
void cvt_w_kernel(const float* __restrict__ Wd, const float* __restrict__ Wu,
                  const float* __restrict__ bu,
                  ushort* __restrict__ WdT, ushort* __restrict__ Wu2T) {
  __shared__ ushort tl[64][72];
  const int rr = threadIdx.x >> 2;
  const int cc = (threadIdx.x & 3) * 16;
  const int bx = blockIdx.x;
  if (bx < 128) {
    const int e  = bx >> 4;
    const int d0 = (bx & 15) * 64;
    const float* src = Wd + ((size_t)e * DM + d0 + rr) * BOT + cc;
    #pragma unroll
    for (int i = 0; i < 4; ++i) {
      float4 v = *(const float4*)(src + i * 4);
      tl[rr][cc + i * 4 + 0] = f2bf(v.x);
      tl[rr][cc + i * 4 + 1] = f2bf(v.y);
      tl[rr][cc + i * 4 + 2] = f2bf(v.z);
      tl[rr][cc + i * 4 + 3] = f2bf(v.w);
    }
    __syncthreads();
    bf16x8 o0, o1;
    #pragma unroll
    for (int k = 0; k < 8; ++k) o0[k] = (short)tl[cc + k][rr];
    #pragma unroll
    for (int k = 0; k < 8; ++k) o1[k] = (short)tl[cc + 8 + k][rr];
    ushort* dst = WdT + ((size_t)e * BOT + rr) * DM + d0 + cc;
    *(bf16x8*)dst       = o0;
    *(bf16x8*)(dst + 8) = o1;
  } else {
    const int b2 = bx - 128;
    const int n0 = (b2 >> 4) * 64;
    const int d0 = (b2 & 15) * 64;
    const int n  = n0 + rr;
    #pragma unroll
    for (int i = 0; i < 4; ++i) {
      float4 v;
      if (n < HD)           v = *(const float4*)(Wu + (size_t)n * DM + d0 + cc + i * 4);
      else if (n < HD + NE) v = *(const float4*)(bu + (size_t)(n - HD) * DM + d0 + cc + i * 4);
      else { v.x = 0.f; v.y = 0.f; v.z = 0.f; v.w = 0.f; }
      tl[rr][cc + i * 4 + 0] = f2bf(v.x);
      tl[rr][cc + i * 4 + 1] = f2bf(v.y);
      tl[rr][cc + i * 4 + 2] = f2bf(v.z);
      tl[rr][cc + i * 4 + 3] = f2bf(v.w);
    }
    __syncthreads();
    bf16x8 o0, o1;
    #pragma unroll
    for (int k = 0; k < 8; ++k) o0[k] = (short)tl[cc + k][rr];
    #pragma unroll
    for (int k = 0; k < 8; ++k) o1[k] = (short)tl[cc + 8 + k][rr];
    ushort* dst = Wu2T + (size_t)(d0 + rr) * HD2 + n0 + cc;
    *(bf16x8*)dst       = o0;
    *(bf16x8*)(dst + 8) = o1;
  }
}

// ---- 128x128 bf16 GEMM, C = A @ B^T, dbuf + counted vmcnt + XCD swizzle -----
// LDS tiles XOR-swizzled (T2, both-sides): source col = sc ^ (sr<<3) (elems),
// read col = (s*32+kg*8) ^ ((lr&7)<<3). 16-way bank conflict -> ~2-way (free).
// EPI=0: Hout[t][col] (ld 576) = bf16( relu(acc+bd[col]) * sg[t][col>>6] )
// EPI=1: Cout[t][col] (ld 1024) = acc
template <int EPI, int NKT, int NBX>
__global__ __launch_bounds__(256)
void gemm_bt(const ushort* __restrict__ A, const ushort* __restrict__ B,
             const float* __restrict__ sg, const float* __restrict__ bd,
             ushort* __restrict__ Hout, float* __restrict__ Cout, int nwg) {
  constexpr int K = NKT * 64;
  __shared__ __attribute__((aligned(16))) ushort sA[2][128 * 64];
  __shared__ __attribute__((aligned(16))) ushort sB[2][128 * 64];
  const int lane = threadIdx.x & 63;
  const int w    = threadIdx.x >> 6;
  const int lb = (blockIdx.x % 8) * (nwg / 8) + blockIdx.x / 8;  // XCD-chunked
  const int tile_m = (lb / NBX) * 128;
  const int tile_n = (lb % NBX) * 128;
  const int wm = (w >> 1) * 64;
  const int wn = (w & 1) * 64;
  const int sr = lane >> 3;                 // 0..7 == staged row & 7
  const int sc = ((lane & 7) * 8) ^ (sr << 3);  // pre-swizzled source col (elems)
  const int lr = lane & 15;
  const int kg = lane >> 4;
  const int swz = (lr & 7) << 3;            // read-side XOR (elems)
  f32x4 acc[4][4] = {};

#define STAGE(buf, kt) do {                                                       \
    const int k0_ = (kt) << 6;                                                    \
    _Pragma("unroll")                                                             \
    for (int c = 0; c < 4; ++c) {                                                 \
      const ushort* ga = A + (size_t)(tile_m + w * 32 + c * 8 + sr) * K + k0_ + sc; \
      __builtin_amdgcn_global_load_lds((const __attribute__((address_space(1))) void*)ga, \
          (__attribute__((address_space(3))) void*)&sA[buf][(w * 32 + c * 8) * 64], 16, 0, 0); \
      const ushort* gb = B + (size_t)(tile_n + w * 32 + c * 8 + sr) * K + k0_ + sc; \
      __builtin_amdgcn_global_load_lds((const __attribute__((address_space(1))) void*)gb, \
          (__attribute__((address_space(3))) void*)&sB[buf][(w * 32 + c * 8) * 64], 16, 0, 0); \
    } } while (0)

  STAGE(0, 0);
  for (int kt = 0; kt < NKT; ++kt) {
    const int cur = kt & 1;
    if (kt + 1 < NKT) {
      STAGE(cur ^ 1, kt + 1);
      asm volatile("s_waitcnt vmcnt(8)" ::: "memory");
    } else {
      asm volatile("s_waitcnt vmcnt(0)" ::: "memory");
    }
    __builtin_amdgcn_s_barrier();
    #pragma unroll
    for (int s = 0; s < 2; ++s) {
      bf16x8 af[4], bfr[4];
      #pragma unroll
      for (int i = 0; i < 4; ++i)
        af[i] = *(const bf16x8*)&sA[cur][(wm + i * 16 + lr) * 64 + ((s * 32 + kg * 8) ^ swz)];
      #pragma unroll
      for (int j = 0; j < 4; ++j)
        bfr[j] = *(const bf16x8*)&sB[cur][(wn + j * 16 + lr) * 64 + ((s * 32 + kg * 8) ^ swz)];
      #pragma unroll
      for (int i = 0; i < 4; ++i)
        #pragma unroll
        for (int j = 0; j < 4; ++j)
          acc[i][j] = __builtin_amdgcn_mfma_f32_16x16x32_bf16(af[i], bfr[j], acc[i][j], 0, 0, 0);
    }
    asm volatile("" ::: "memory");
    __builtin_amdgcn_s_barrier();
  }
#undef STAGE

  if (EPI == 0) {
    const int e = (tile_n + wn) >> 6;
    float bdv[4];
    #pragma unroll
    for (int j = 0; j < 4; ++j) bdv[j] = bd[tile_n + wn + j * 16 + lr];
    #pragma unroll
    for (int i = 0; i < 4; ++i) {
      #pragma unroll
      for (int r = 0; r < 4; ++r) {
        const int t = tile_m + wm + i * 16 + kg * 4 + r;
        const float sglv = sg[(size_t)t * NE + e];
        #pragma unroll
        for (int j = 0; j < 4; ++j) {
          float v = fmaxf(acc[i][j][r] + bdv[j], 0.f) * sglv;
          Hout[(size_t)t * HD2 + tile_n + wn + j * 16 + lr] = f2bf(v);
        }
      }
    }
  } else {
    #pragma unroll
    for (int i = 0; i < 4; ++i) {
      #pragma unroll
      for (int r = 0; r < 4; ++r) {
        const int t = tile_m + wm + i * 16 + kg * 4 + r;
        #pragma unroll
        for (int j = 0; j < 4; ++j)
          Cout[(size_t)t * DM + tile_n + wn + j * 16 + lr] = acc[i][j][r];
      }
    }
  }
}

extern "C" void kernel_launch(void* const* d_in, const int* in_sizes, int n_in,
                              void* d_out, int out_size, void* d_ws, size_t ws_size,
                              hipStream_t stream) {
  const float* x  = (const float*)d_in[0];
  const float* wg = (const float*)d_in[1];
  // d_in[2] = w_noise: unused (reference gates on clean logits)
  const float* Wd = (const float*)d_in[3];
  const float* bd = (const float*)d_in[4];
  const float* Wu = (const float*)d_in[5];
  const float* bu = (const float*)d_in[6];
  float* out = (float*)d_out;

  char* ws = (char*)d_ws;
  ushort* Xb   = (ushort*)(ws);                      // 16 MB
  ushort* H2   = (ushort*)(ws + 16777216);           // 9.44 MB
  ushort* WdT  = (ushort*)(ws + 26214400);           // 1 MB
  ushort* Wu2T = (ushort*)(ws + 27262976);           // 1.18 MB
  float*  sgw  = (float*) (ws + 28442624);           // 256 KB

  prep_kernel <<<dim3(T_TOK / PW), dim3(256), 0, stream>>>(x, wg, Xb, sgw, H2);
  cvt_w_kernel<<<dim3(272),        dim3(256), 0, stream>>>(Wd, Wu, bu, WdT, Wu2T);

  // H2[:, :512] = sg .* relu(X @ WdT^T + bd):  M=8192 N=512 K=1024
  gemm_bt<0, 16, 4><<<dim3(256), dim3(256), 0, stream>>>(Xb, WdT, sgw, bd, H2, nullptr, 256);
  // out = H2 @ Wu2T^T (bias rows folded):      M=8192 N=1024 K=576
  gemm_bt<1, 9, 8><<<dim3(512), dim3(256), 0, stream>>>(H2, Wu2T, sgw, nullptr, nullptr, out, 512);
}

// Round 5
// 50.384 us; speedup vs baseline: 1.9448x; 1.1024x over previous
//
#include <hip/hip_runtime.h>
#include <stdint.h>

#define T_TOK 8192
#define DM    1024
#define NE    8
#define BOT   64
#define HD    512
#define HD2   576   // 512 expert cols + 8 sg cols + 56 zero pad (bias folded into K)
#define PW    8     // tokens per prep block
#define NPREP (T_TOK / PW)   // 1024 prep blocks

typedef __attribute__((ext_vector_type(8))) short bf16x8;
typedef __attribute__((ext_vector_type(4))) short bf16x4;
typedef __attribute__((ext_vector_type(4))) float f32x4;

__device__ __forceinline__ ushort f2bf(float f) {
  union { float f; uint32_t u; } v; v.f = f;
  uint32_t r = (v.u + 0x7fffu + ((v.u >> 16) & 1u)) >> 16;
  return (ushort)r;
}

// ---- merged prep (blocks 0..1023) + weight transposes (1024..1295) ---------
// prep: X->bf16, fp32 gating with reg-resident wg rows, top-2, H2 tail cols.
// cvt:  WdT[e*64+b][d] = bf16(Wd[e][d][b]);  Wu2T[d][n](ld 576) = Wu/bu/0.
__global__ __launch_bounds__(256, 2)
void prep_cvt_kernel(const float* __restrict__ x, const float* __restrict__ wg,
                     const float* __restrict__ Wd, const float* __restrict__ Wu,
                     const float* __restrict__ bu,
                     ushort* __restrict__ Xb, float* __restrict__ sg,
                     ushort* __restrict__ H2, ushort* __restrict__ WdT,
                     ushort* __restrict__ Wu2T) {
  __shared__ float part[4][PW][NE];
  __shared__ float sgl[PW][NE];
  __shared__ ushort tl[64][72];
  if (blockIdx.x < NPREP) {
    const int lane = threadIdx.x & 63;
    const int w    = threadIdx.x >> 6;
    const int t0   = blockIdx.x * PW;
    const int dd   = w * 256 + lane * 4;
    float4 wgr[4][2];
    #pragma unroll
    for (int j = 0; j < 4; ++j) {
      wgr[j][0] = *(const float4*)(wg + (size_t)(dd + j) * NE);
      wgr[j][1] = *(const float4*)(wg + (size_t)(dd + j) * NE + 4);
    }
    const int ebit = ((lane & 1) << 2) | (lane & 2) | ((lane >> 2) & 1);
    const float* xp = x + (size_t)t0 * DM + dd;
    float4 xv = *(const float4*)xp;
    #pragma unroll
    for (int tk = 0; tk < PW; ++tk) {
      float4 nxt = {};
      if (tk + 1 < PW) nxt = *(const float4*)(xp + (size_t)(tk + 1) * DM);
      bf16x4 xb;
      xb[0] = (short)f2bf(xv.x); xb[1] = (short)f2bf(xv.y);
      xb[2] = (short)f2bf(xv.z); xb[3] = (short)f2bf(xv.w);
      *(bf16x4*)(Xb + (size_t)(t0 + tk) * DM + dd) = xb;
      float a[NE] = {};
      const float* xs = (const float*)&xv;
      #pragma unroll
      for (int j = 0; j < 4; ++j) {
        const float xj = xs[j];
        const float* wr = (const float*)&wgr[j][0];
        #pragma unroll
        for (int e = 0; e < NE; ++e) a[e] += xj * wr[e];
      }
      float t0v[4];
      #pragma unroll
      for (int j = 0; j < 4; ++j) {
        float send = (lane & 1) ? a[j] : a[j + 4];
        float keep = (lane & 1) ? a[j + 4] : a[j];
        t0v[j] = keep + __shfl_xor(send, 1);
      }
      float t1v[2];
      #pragma unroll
      for (int j = 0; j < 2; ++j) {
        float send = (lane & 2) ? t0v[j] : t0v[j + 2];
        float keep = (lane & 2) ? t0v[j + 2] : t0v[j];
        t1v[j] = keep + __shfl_xor(send, 2);
      }
      {
        float send = (lane & 4) ? t1v[0] : t1v[1];
        float keep = (lane & 4) ? t1v[1] : t1v[0];
        float t2 = keep + __shfl_xor(send, 4);
        t2 += __shfl_xor(t2, 8);
        t2 += __shfl_xor(t2, 16);
        t2 += __shfl_xor(t2, 32);
        if (lane < NE) part[w][tk][ebit] = t2;
      }
      xv = nxt;
    }
    __syncthreads();
    const int tid = threadIdx.x;
    if (tid < PW) {
      float lg[NE];
      #pragma unroll
      for (int e = 0; e < NE; ++e)
        lg[e] = part[0][tid][e] + part[1][tid][e] + part[2][tid][e] + part[3][tid][e];
      int e0 = 0; float l0 = lg[0];
      #pragma unroll
      for (int e = 1; e < NE; ++e) if (lg[e] > l0) { l0 = lg[e]; e0 = e; }
      int e1 = -1; float l1 = -3.4e38f;
      #pragma unroll
      for (int e = 0; e < NE; ++e) if (e != e0 && lg[e] > l1) { l1 = lg[e]; e1 = e; }
      const float p1  = __expf(l1 - l0);
      const float inv = 1.f / (1.f + p1);
      const float g0 = 0.5f * inv, g1 = 0.5f * p1 * inv;   // ADAPTER_SCALE folded
      float g[NE];
      #pragma unroll
      for (int e = 0; e < NE; ++e) g[e] = (e == e0) ? g0 : ((e == e1) ? g1 : 0.f);
      #pragma unroll
      for (int e = 0; e < NE; ++e) sgl[tid][e] = g[e];
      *(float4*)(sg + (size_t)(t0 + tid) * NE)     = *(float4*)&g[0];
      *(float4*)(sg + (size_t)(t0 + tid) * NE + 4) = *(float4*)&g[4];
    }
    __syncthreads();
    if (tid < PW * 8) {
      const int tk = tid >> 3, ch = tid & 7;
      bf16x8 v;
      #pragma unroll
      for (int k = 0; k < 8; ++k)
        v[k] = (ch == 0) ? (short)f2bf(sgl[tk][k]) : (short)0;
      *(bf16x8*)(H2 + (size_t)(t0 + tk) * HD2 + HD + ch * 8) = v;
    }
  } else {
    const int rr = threadIdx.x >> 2;
    const int cc = (threadIdx.x & 3) * 16;
    const int bx = blockIdx.x - NPREP;
    if (bx < 128) {
      const int e  = bx >> 4;
      const int d0 = (bx & 15) * 64;
      const float* src = Wd + ((size_t)e * DM + d0 + rr) * BOT + cc;
      #pragma unroll
      for (int i = 0; i < 4; ++i) {
        float4 v = *(const float4*)(src + i * 4);
        tl[rr][cc + i * 4 + 0] = f2bf(v.x);
        tl[rr][cc + i * 4 + 1] = f2bf(v.y);
        tl[rr][cc + i * 4 + 2] = f2bf(v.z);
        tl[rr][cc + i * 4 + 3] = f2bf(v.w);
      }
      __syncthreads();
      bf16x8 o0, o1;
      #pragma unroll
      for (int k = 0; k < 8; ++k) o0[k] = (short)tl[cc + k][rr];
      #pragma unroll
      for (int k = 0; k < 8; ++k) o1[k] = (short)tl[cc + 8 + k][rr];
      ushort* dst = WdT + ((size_t)e * BOT + rr) * DM + d0 + cc;
      *(bf16x8*)dst       = o0;
      *(bf16x8*)(dst + 8) = o1;
    } else {
      const int b2 = bx - 128;
      const int n0 = (b2 >> 4) * 64;
      const int d0 = (b2 & 15) * 64;
      const int n  = n0 + rr;
      #pragma unroll
      for (int i = 0; i < 4; ++i) {
        float4 v;
        if (n < HD)           v = *(const float4*)(Wu + (size_t)n * DM + d0 + cc + i * 4);
        else if (n < HD + NE) v = *(const float4*)(bu + (size_t)(n - HD) * DM + d0 + cc + i * 4);
        else { v.x = 0.f; v.y = 0.f; v.z = 0.f; v.w = 0.f; }
        tl[rr][cc + i * 4 + 0] = f2bf(v.x);
        tl[rr][cc + i * 4 + 1] = f2bf(v.y);
        tl[rr][cc + i * 4 + 2] = f2bf(v.z);
        tl[rr][cc + i * 4 + 3] = f2bf(v.w);
      }
      __syncthreads();
      bf16x8 o0, o1;
      #pragma unroll
      for (int k = 0; k < 8; ++k) o0[k] = (short)tl[cc + k][rr];
      #pragma unroll
      for (int k = 0; k < 8; ++k) o1[k] = (short)tl[cc + 8 + k][rr];
      ushort* dst = Wu2T + (size_t)(d0 + rr) * HD2 + n0 + cc;
      *(bf16x8*)dst       = o0;
      *(bf16x8*)(dst + 8) = o1;
    }
  }
}

// ---- 128(M)x64(N) bf16 GEMM, C = A @ B^T, 3-deep pipeline + XCD swizzle -----
// Triple-buffered LDS (72KB, 2 blocks/CU); STAGE kt+2 in flight; counted vmcnt.
// LDS XOR-swizzled both-sides (rule 21): src col = sc ^ (sr<<3), read ^= swz.
// EPI=0: Hout[t][col] (ld 576) = bf16( relu(acc+bd[col]) * sg[t][col>>6] )
// EPI=1: Cout[t][col] (ld 1024) = acc   (bias folded into K via H2 tail cols)
template <int EPI, int NKT, int NBX>
__global__ __launch_bounds__(256)
void gemm_bt(const ushort* __restrict__ A, const ushort* __restrict__ B,
             const float* __restrict__ sg, const float* __restrict__ bd,
             ushort* __restrict__ Hout, float* __restrict__ Cout, int nwg) {
  constexpr int K = NKT * 64;
  __shared__ __attribute__((aligned(16))) ushort sA[3][128 * 64];
  __shared__ __attribute__((aligned(16))) ushort sB[3][64 * 64];
  const int lane = threadIdx.x & 63;
  const int w    = threadIdx.x >> 6;
  const int lb = (blockIdx.x % 8) * (nwg / 8) + blockIdx.x / 8;  // XCD-chunked
  const int tile_m = (lb / NBX) * 128;
  const int tile_n = (lb % NBX) * 64;
  const int wm = (w >> 1) * 64;
  const int wn = (w & 1) * 32;
  const int sr = lane >> 3;
  const int sc = ((lane & 7) * 8) ^ (sr << 3);   // pre-swizzled source col
  const int lr = lane & 15;
  const int kg = lane >> 4;
  const int swz = (lr & 7) << 3;                 // read-side XOR (elems)
  f32x4 acc[4][2] = {};

#define STAGE(buf, kt) do {                                                       \
    const int k0_ = (kt) << 6;                                                    \
    _Pragma("unroll")                                                             \
    for (int c = 0; c < 4; ++c) {                                                 \
      const ushort* ga = A + (size_t)(tile_m + w * 32 + c * 8 + sr) * K + k0_ + sc; \
      __builtin_amdgcn_global_load_lds((const __attribute__((address_space(1))) void*)ga, \
          (__attribute__((address_space(3))) void*)&sA[buf][(w * 32 + c * 8) * 64], 16, 0, 0); \
    }                                                                             \
    _Pragma("unroll")                                                             \
    for (int c = 0; c < 2; ++c) {                                                 \
      const ushort* gb = B + (size_t)(tile_n + w * 16 + c * 8 + sr) * K + k0_ + sc; \
      __builtin_amdgcn_global_load_lds((const __attribute__((address_space(1))) void*)gb, \
          (__attribute__((address_space(3))) void*)&sB[buf][(w * 16 + c * 8) * 64], 16, 0, 0); \
    } } while (0)

  STAGE(0, 0);
  STAGE(1, 1);
  for (int kt = 0; kt < NKT; ++kt) {
    const int cur = kt % 3;
    if (kt + 2 < NKT) {
      STAGE((kt + 2) % 3, kt + 2);
      asm volatile("s_waitcnt vmcnt(12)" ::: "memory");  // kt's 6 landed; kt+1,kt+2 in flight
    } else if (kt + 1 < NKT) {
      asm volatile("s_waitcnt vmcnt(6)" ::: "memory");
    } else {
      asm volatile("s_waitcnt vmcnt(0)" ::: "memory");
    }
    __builtin_amdgcn_s_barrier();
    #pragma unroll
    for (int s = 0; s < 2; ++s) {
      bf16x8 af[4], bfr[2];
      #pragma unroll
      for (int i = 0; i < 4; ++i)
        af[i] = *(const bf16x8*)&sA[cur][(wm + i * 16 + lr) * 64 + ((s * 32 + kg * 8) ^ swz)];
      #pragma unroll
      for (int j = 0; j < 2; ++j)
        bfr[j] = *(const bf16x8*)&sB[cur][(wn + j * 16 + lr) * 64 + ((s * 32 + kg * 8) ^ swz)];
      #pragma unroll
      for (int i = 0; i < 4; ++i)
        #pragma unroll
        for (int j = 0; j < 2; ++j)
          acc[i][j] = __builtin_amdgcn_mfma_f32_16x16x32_bf16(af[i], bfr[j], acc[i][j], 0, 0, 0);
    }
    asm volatile("" ::: "memory");
    __builtin_amdgcn_s_barrier();
  }
#undef STAGE

  if (EPI == 0) {
    const int e = tile_n >> 6;               // 64-col tile spans one expert
    float bdv[2];
    #pragma unroll
    for (int j = 0; j < 2; ++j) bdv[j] = bd[tile_n + wn + j * 16 + lr];
    #pragma unroll
    for (int i = 0; i < 4; ++i) {
      #pragma unroll
      for (int r = 0; r < 4; ++r) {
        const int t = tile_m + wm + i * 16 + kg * 4 + r;
        const float sglv = sg[(size_t)t * NE + e];
        #pragma unroll
        for (int j = 0; j < 2; ++j) {
          float v = fmaxf(acc[i][j][r] + bdv[j], 0.f) * sglv;
          Hout[(size_t)t * HD2 + tile_n + wn + j * 16 + lr] = f2bf(v);
        }
      }
    }
  } else {
    #pragma unroll
    for (int i = 0; i < 4; ++i) {
      #pragma unroll
      for (int r = 0; r < 4; ++r) {
        const int t = tile_m + wm + i * 16 + kg * 4 + r;
        #pragma unroll
        for (int j = 0; j < 2; ++j)
          Cout[(size_t)t * DM + tile_n + wn + j * 16 + lr] = acc[i][j][r];
      }
    }
  }
}

extern "C" void kernel_launch(void* const* d_in, const int* in_sizes, int n_in,
                              void* d_out, int out_size, void* d_ws, size_t ws_size,
                              hipStream_t stream) {
  const float* x  = (const float*)d_in[0];
  const float* wg = (const float*)d_in[1];
  // d_in[2] = w_noise: unused (reference gates on clean logits)
  const float* Wd = (const float*)d_in[3];
  const float* bd = (const float*)d_in[4];
  const float* Wu = (const float*)d_in[5];
  const float* bu = (const float*)d_in[6];
  float* out = (float*)d_out;

  char* ws = (char*)d_ws;
  ushort* Xb   = (ushort*)(ws);                      // 16 MB
  ushort* H2   = (ushort*)(ws + 16777216);           // 9.44 MB
  ushort* WdT  = (ushort*)(ws + 26214400);           // 1 MB
  ushort* Wu2T = (ushort*)(ws + 27262976);           // 1.18 MB
  float*  sgw  = (float*) (ws + 28442624);           // 256 KB

  prep_cvt_kernel<<<dim3(NPREP + 272), dim3(256), 0, stream>>>(
      x, wg, Wd, Wu, bu, Xb, sgw, H2, WdT, Wu2T);

  // H2[:, :512] = sg .* relu(X @ WdT^T + bd):  M=8192 N=512 K=1024
  gemm_bt<0, 16, 8><<<dim3(512), dim3(256), 0, stream>>>(Xb, WdT, sgw, bd, H2, nullptr, 512);
  // out = H2 @ Wu2T^T (bias rows folded):      M=8192 N=1024 K=576
  gemm_bt<1, 9, 16><<<dim3(1024), dim3(256), 0, stream>>>(H2, Wu2T, sgw, nullptr, nullptr, out, 1024);
}